// Round 1
// baseline (2218.223 us; speedup 1.0000x reference)
//
#include <hip/hip_runtime.h>

#define NN 163842
#define NE 983040

// ---------------- degree ----------------
__global__ __launch_bounds__(256) void deg_kernel(const int* __restrict__ dst,
                                                  float* __restrict__ deg, int E) {
    int e = blockIdx.x * blockDim.x + threadIdx.x;
    if (e < E) atomicAdd(&deg[dst[e]], 1.0f);
}

// ---------------- xw = h @ g : [n,cin] x [cin,kc] -> [n,kc] ----------------
__global__ __launch_bounds__(256) void xw_kernel(const float* __restrict__ h,
                                                 const float* __restrict__ g,
                                                 float* __restrict__ xw,
                                                 int n, int cin, int kc) {
    long t = (long)blockIdx.x * blockDim.x + threadIdx.x;
    long total = (long)n * kc;
    if (t >= total) return;
    int j = (int)(t % kc);
    long row = t / kc;
    const float* hr = h + row * cin;
    float acc = 0.0f;
    for (int c = 0; c < cin; ++c)
        acc = fmaf(hr[c], g[(long)c * kc + j], acc);
    xw[t] = acc;
}

// ---------------- per-edge message + scatter-add ----------------
// blockDim.x = 256, cout threads per edge (cout in {32,64})
__global__ __launch_bounds__(256) void edge_kernel(const float* __restrict__ xw,
                                                   const float* __restrict__ ea,
                                                   const int* __restrict__ src,
                                                   const int* __restrict__ dst,
                                                   const float* __restrict__ mu,
                                                   const float* __restrict__ sigma,
                                                   float* __restrict__ agg,
                                                   int E, int cout, int kc) {
    int per = blockDim.x / cout;                 // edges per block
    int le  = threadIdx.x / cout;
    int o   = threadIdx.x - le * cout;
    long e  = (long)blockIdx.x * per + le;
    if (e >= E) return;

    int s = src[e];
    int d = dst[e];
    float p0 = ea[2 * e];
    float p1 = ea[2 * e + 1];

    const float* xr = xw + (long)s * kc + o;
    float m = 0.0f;
#pragma unroll
    for (int k = 0; k < 3; ++k) {
        float d0 = p0 - mu[2 * k];
        float d1 = p1 - mu[2 * k + 1];
        float s0 = sigma[2 * k];
        float s1 = sigma[2 * k + 1];
        float q  = d0 * d0 / (1e-15f + s0 * s0) + d1 * d1 / (1e-15f + s1 * s1);
        float gk = __expf(-0.5f * q);
        m = fmaf(gk, xr[k * cout], m);
    }
    atomicAdd(&agg[(long)d * cout + o], m);
}

// ---------------- node update: relu(agg/deg + h@root + b) ----------------
__global__ __launch_bounds__(256) void node_kernel(const float* __restrict__ h,
                                                   const float* __restrict__ agg,
                                                   const float* __restrict__ deg,
                                                   const float* __restrict__ root,
                                                   const float* __restrict__ bias,
                                                   float* __restrict__ out,
                                                   int n, int cin, int cout) {
    long t = (long)blockIdx.x * blockDim.x + threadIdx.x;
    long total = (long)n * cout;
    if (t >= total) return;
    int o = (int)(t % cout);
    long row = t / cout;
    float v = agg[t] / fmaxf(deg[row], 1.0f);
    const float* hr = h + row * cin;
    for (int c = 0; c < cin; ++c)
        v = fmaf(hr[c], root[(long)c * cout + o], v);
    v += bias[o];
    out[t] = fmaxf(v, 0.0f);
}

// ---------------- final FC (64->2) + log_softmax ----------------
__global__ __launch_bounds__(256) void final_kernel(const float* __restrict__ h,
                                                    const float* __restrict__ fcw,
                                                    const float* __restrict__ fcb,
                                                    float* __restrict__ out, int n) {
    int i = blockIdx.x * blockDim.x + threadIdx.x;
    if (i >= n) return;
    const float* hr = h + (long)i * 64;
    float l0 = fcb[0];
    float l1 = fcb[1];
#pragma unroll
    for (int j = 0; j < 64; ++j) {
        float hv = hr[j];
        l0 = fmaf(hv, fcw[2 * j], l0);
        l1 = fmaf(hv, fcw[2 * j + 1], l1);
    }
    float mx  = fmaxf(l0, l1);
    float lse = mx + logf(__expf(l0 - mx) + __expf(l1 - mx));
    out[2 * (long)i]     = l0 - lse;
    out[2 * (long)i + 1] = l1 - lse;
}

extern "C" void kernel_launch(void* const* d_in, const int* in_sizes, int n_in,
                              void* d_out, int out_size, void* d_ws, size_t ws_size,
                              hipStream_t stream) {
    const float* x   = (const float*)d_in[0];
    const int*   ei  = (const int*)d_in[1];          // [2, E] int32
    const float* ea  = (const float*)d_in[2];        // [E, 2]
    const float* g_[3]  = {(const float*)d_in[3],  (const float*)d_in[8],  (const float*)d_in[13]};
    const float* mu_[3] = {(const float*)d_in[4],  (const float*)d_in[9],  (const float*)d_in[14]};
    const float* sg_[3] = {(const float*)d_in[5],  (const float*)d_in[10], (const float*)d_in[15]};
    const float* rt_[3] = {(const float*)d_in[6],  (const float*)d_in[11], (const float*)d_in[16]};
    const float* bs_[3] = {(const float*)d_in[7],  (const float*)d_in[12], (const float*)d_in[17]};
    const float* fcw = (const float*)d_in[18];
    const float* fcb = (const float*)d_in[19];
    float* out = (float*)d_out;

    const int cins[4] = {22, 32, 64, 64};

    // workspace carve-up
    char* w = (char*)d_ws;
    size_t off = 0;
    auto carve = [&](size_t bytes) -> float* {
        float* p = (float*)(w + off);
        off += (bytes + 255) & ~(size_t)255;
        return p;
    };
    float* deg = carve((size_t)NN * 4);
    float* xw  = carve((size_t)NN * 192 * 4);
    float* agg = carve((size_t)NN * 64 * 4);
    float* hA  = carve((size_t)NN * 64 * 4);
    float* hB  = carve((size_t)NN * 64 * 4);
    (void)ws_size; (void)in_sizes; (void)n_in; (void)out_size;

    const int* src = ei;
    const int* dst = ei + NE;

    // degree (shared across layers)
    hipMemsetAsync(deg, 0, (size_t)NN * 4, stream);
    deg_kernel<<<(NE + 255) / 256, 256, 0, stream>>>(dst, deg, NE);

    const float* hin = x;
    float* hbuf[2] = {hA, hB};
    for (int layer = 0; layer < 3; ++layer) {
        int cin  = cins[layer];
        int cout = cins[layer + 1];
        int kc   = 3 * cout;
        float* hout = hbuf[layer & 1];

        long total_xw = (long)NN * kc;
        xw_kernel<<<(int)((total_xw + 255) / 256), 256, 0, stream>>>(hin, g_[layer], xw, NN, cin, kc);

        hipMemsetAsync(agg, 0, (size_t)NN * cout * 4, stream);

        int per = 256 / cout;
        int eblocks = (NE + per - 1) / per;
        edge_kernel<<<eblocks, 256, 0, stream>>>(xw, ea, src, dst, mu_[layer], sg_[layer],
                                                 agg, NE, cout, kc);

        long total_node = (long)NN * cout;
        node_kernel<<<(int)((total_node + 255) / 256), 256, 0, stream>>>(
            hin, agg, deg, rt_[layer], bs_[layer], hout, NN, cin, cout);

        hin = hout;
    }

    final_kernel<<<(NN + 255) / 256, 256, 0, stream>>>(hin, fcw, fcb, out, NN);
}

// Round 2
// 1017.838 us; speedup vs baseline: 2.1793x; 2.1793x over previous
//
#include <hip/hip_runtime.h>

#define NN 163842
#define NE 983040

// ---------------- degree ----------------
__global__ __launch_bounds__(256) void deg_kernel(const int* __restrict__ dst,
                                                  float* __restrict__ deg, int E) {
    int e = blockIdx.x * blockDim.x + threadIdx.x;
    if (e < E) atomicAdd(&deg[dst[e]], 1.0f);
}

// ---------------- per-edge gaussians, pre-divided by deg[dst] ----------------
__global__ __launch_bounds__(256) void gauss_kernel(const float* __restrict__ ea,
                                                    const int* __restrict__ dst,
                                                    const float* __restrict__ deg,
                                                    const float* __restrict__ mu,
                                                    const float* __restrict__ sigma,
                                                    float* __restrict__ gs, int E) {
    int e = blockIdx.x * blockDim.x + threadIdx.x;
    if (e >= E) return;
    float p0 = ea[2 * e];
    float p1 = ea[2 * e + 1];
    float inv = 1.0f / fmaxf(deg[dst[e]], 1.0f);
#pragma unroll
    for (int k = 0; k < 3; ++k) {
        float d0 = p0 - mu[2 * k];
        float d1 = p1 - mu[2 * k + 1];
        float s0 = sigma[2 * k];
        float s1 = sigma[2 * k + 1];
        float q  = d0 * d0 / (1e-15f + s0 * s0) + d1 * d1 / (1e-15f + s1 * s1);
        gs[3 * (long)e + k] = __expf(-0.5f * q) * inv;
    }
}

// ---------------- xw = h @ g, wave-per-row, g columns in registers ----------------
// KC <= 64*JPT. Each wave owns one row; thread lane holds g[:, lane + 64*p].
template <int CIN, int KC, int JPT>
__global__ __launch_bounds__(256) void xw_wave(const float* __restrict__ h,
                                               const float* __restrict__ g,
                                               float* __restrict__ xw, int n) {
    const int lane = threadIdx.x & 63;
    const int wid  = threadIdx.x >> 6;
    float greg[CIN * JPT];
#pragma unroll
    for (int c = 0; c < CIN; ++c)
#pragma unroll
        for (int p = 0; p < JPT; ++p) {
            int j = lane + 64 * p;
            greg[c * JPT + p] = (j < KC) ? g[(long)c * KC + j] : 0.0f;
        }
    const int nwaves = gridDim.x * 4;
    for (int row = blockIdx.x * 4 + wid; row < n; row += nwaves) {
        int rowu = __builtin_amdgcn_readfirstlane(row);   // force scalar h loads
        const float* hr = h + (long)rowu * CIN;
        float acc[JPT];
#pragma unroll
        for (int p = 0; p < JPT; ++p) acc[p] = 0.0f;
#pragma unroll
        for (int c = 0; c < CIN; ++c) {
            float hv = hr[c];
#pragma unroll
            for (int p = 0; p < JPT; ++p) acc[p] = fmaf(hv, greg[c * JPT + p], acc[p]);
        }
        float* xr = xw + (long)rowu * KC;
#pragma unroll
        for (int p = 0; p < JPT; ++p) {
            int j = lane + 64 * p;
            if (j < KC) xr[j] = acc[p];
        }
    }
}

// ---------------- per-edge message + scatter-add ----------------
template <int COUT>
__global__ __launch_bounds__(256) void edge_kernel(const float* __restrict__ xw,
                                                   const int* __restrict__ src,
                                                   const int* __restrict__ dst,
                                                   const float* __restrict__ gs,
                                                   float* __restrict__ agg, int E) {
    const int per = 256 / COUT;
    int le = threadIdx.x / COUT;
    int o  = threadIdx.x % COUT;
    long e = (long)blockIdx.x * per + le;
    if (e >= E) return;
    int s = src[e];
    int d = dst[e];
    float g0 = gs[3 * e];
    float g1 = gs[3 * e + 1];
    float g2 = gs[3 * e + 2];
    const float* xr = xw + (long)s * (3 * COUT) + o;
    float m = g0 * xr[0];
    m = fmaf(g1, xr[COUT], m);
    m = fmaf(g2, xr[2 * COUT], m);
    atomicAdd(&agg[(long)d * COUT + o], m);
}

// ---------------- node update: relu(agg + h@root + b), wave-per-row(s) ----------------
template <int CIN, int COUT>
__global__ __launch_bounds__(256) void node_wave(const float* __restrict__ h,
                                                 const float* __restrict__ agg,
                                                 const float* __restrict__ root,
                                                 const float* __restrict__ bias,
                                                 float* __restrict__ out, int n) {
    constexpr int ROWS = 64 / COUT;      // rows per wave (1 or 2)
    const int lane = threadIdx.x & 63;
    const int wid  = threadIdx.x >> 6;
    const int o    = lane % COUT;
    const int rsub = lane / COUT;
    float rreg[CIN];
#pragma unroll
    for (int c = 0; c < CIN; ++c) rreg[c] = root[(long)c * COUT + o];
    float b = bias[o];
    const int nwaves = gridDim.x * 4;
    for (int rowb = (blockIdx.x * 4 + wid) * ROWS; rowb < n; rowb += nwaves * ROWS) {
        int row = rowb + rsub;
        if (ROWS == 1) row = __builtin_amdgcn_readfirstlane(row);
        const float* hr = h + (long)row * CIN;
        float v = agg[(long)row * COUT + o];
#pragma unroll
        for (int c = 0; c < CIN; ++c) v = fmaf(hr[c], rreg[c], v);
        v += b;
        out[(long)row * COUT + o] = fmaxf(v, 0.0f);
    }
}

// ---------------- final FC (64->2) + log_softmax ----------------
__global__ __launch_bounds__(256) void final_kernel(const float* __restrict__ h,
                                                    const float* __restrict__ fcw,
                                                    const float* __restrict__ fcb,
                                                    float* __restrict__ out, int n) {
    int i = blockIdx.x * blockDim.x + threadIdx.x;
    if (i >= n) return;
    const float4* h4 = (const float4*)(h + (long)i * 64);
    float l0 = fcb[0];
    float l1 = fcb[1];
#pragma unroll
    for (int j4 = 0; j4 < 16; ++j4) {
        float4 hv = h4[j4];
        l0 = fmaf(hv.x, fcw[8 * j4 + 0], l0);
        l1 = fmaf(hv.x, fcw[8 * j4 + 1], l1);
        l0 = fmaf(hv.y, fcw[8 * j4 + 2], l0);
        l1 = fmaf(hv.y, fcw[8 * j4 + 3], l1);
        l0 = fmaf(hv.z, fcw[8 * j4 + 4], l0);
        l1 = fmaf(hv.z, fcw[8 * j4 + 5], l1);
        l0 = fmaf(hv.w, fcw[8 * j4 + 6], l0);
        l1 = fmaf(hv.w, fcw[8 * j4 + 7], l1);
    }
    float mx  = fmaxf(l0, l1);
    float lse = mx + logf(__expf(l0 - mx) + __expf(l1 - mx));
    out[2 * (long)i]     = l0 - lse;
    out[2 * (long)i + 1] = l1 - lse;
}

extern "C" void kernel_launch(void* const* d_in, const int* in_sizes, int n_in,
                              void* d_out, int out_size, void* d_ws, size_t ws_size,
                              hipStream_t stream) {
    const float* x   = (const float*)d_in[0];
    const int*   ei  = (const int*)d_in[1];          // [2, E]
    const float* ea  = (const float*)d_in[2];        // [E, 2]
    const float* g_[3]  = {(const float*)d_in[3],  (const float*)d_in[8],  (const float*)d_in[13]};
    const float* mu_[3] = {(const float*)d_in[4],  (const float*)d_in[9],  (const float*)d_in[14]};
    const float* sg_[3] = {(const float*)d_in[5],  (const float*)d_in[10], (const float*)d_in[15]};
    const float* rt_[3] = {(const float*)d_in[6],  (const float*)d_in[11], (const float*)d_in[16]};
    const float* bs_[3] = {(const float*)d_in[7],  (const float*)d_in[12], (const float*)d_in[17]};
    const float* fcw = (const float*)d_in[18];
    const float* fcb = (const float*)d_in[19];
    float* out = (float*)d_out;

    // workspace carve-up
    char* w = (char*)d_ws;
    size_t off = 0;
    auto carve = [&](size_t bytes) -> float* {
        float* p = (float*)(w + off);
        off += (bytes + 255) & ~(size_t)255;
        return p;
    };
    float* deg = carve((size_t)NN * 4);
    float* xw  = carve((size_t)NN * 192 * 4);
    float* agg = carve((size_t)NN * 64 * 4);
    float* hA  = carve((size_t)NN * 64 * 4);
    float* hB  = carve((size_t)NN * 64 * 4);
    float* gs  = carve((size_t)NE * 3 * 4);
    (void)ws_size; (void)in_sizes; (void)n_in; (void)out_size;

    const int* src = ei;
    const int* dst = ei + NE;

    hipMemsetAsync(deg, 0, (size_t)NN * 4, stream);
    deg_kernel<<<(NE + 255) / 256, 256, 0, stream>>>(dst, deg, NE);

    const int GRID = 1024;   // grid-stride waves: 4096 waves, ~40 rows each

    // ---------------- layer 0: 22 -> 32 ----------------
    gauss_kernel<<<(NE + 255) / 256, 256, 0, stream>>>(ea, dst, deg, mu_[0], sg_[0], gs, NE);
    xw_wave<22, 96, 2><<<GRID, 256, 0, stream>>>(x, g_[0], xw, NN);
    hipMemsetAsync(agg, 0, (size_t)NN * 32 * 4, stream);
    edge_kernel<32><<<(NE * 32 + 255) / 256, 256, 0, stream>>>(xw, src, dst, gs, agg, NE);
    node_wave<22, 32><<<GRID, 256, 0, stream>>>(x, agg, rt_[0], bs_[0], hA, NN);

    // ---------------- layer 1: 32 -> 64 ----------------
    gauss_kernel<<<(NE + 255) / 256, 256, 0, stream>>>(ea, dst, deg, mu_[1], sg_[1], gs, NE);
    xw_wave<32, 192, 3><<<GRID, 256, 0, stream>>>(hA, g_[1], xw, NN);
    hipMemsetAsync(agg, 0, (size_t)NN * 64 * 4, stream);
    edge_kernel<64><<<(NE * 64 + 255) / 256, 256, 0, stream>>>(xw, src, dst, gs, agg, NE);
    node_wave<32, 64><<<GRID, 256, 0, stream>>>(hA, agg, rt_[1], bs_[1], hB, NN);

    // ---------------- layer 2: 64 -> 64 ----------------
    gauss_kernel<<<(NE + 255) / 256, 256, 0, stream>>>(ea, dst, deg, mu_[2], sg_[2], gs, NE);
    xw_wave<64, 192, 3><<<GRID, 256, 0, stream>>>(hB, g_[2], xw, NN);
    hipMemsetAsync(agg, 0, (size_t)NN * 64 * 4, stream);
    edge_kernel<64><<<(NE * 64 + 255) / 256, 256, 0, stream>>>(xw, src, dst, gs, agg, NE);
    node_wave<64, 64><<<GRID, 256, 0, stream>>>(hB, agg, rt_[2], bs_[2], hA, NN);

    final_kernel<<<(NN + 255) / 256, 256, 0, stream>>>(hA, fcw, fcb, out, NN);
}